// Round 6
// baseline (263.301 us; speedup 1.0000x reference)
//
#include <hip/hip_runtime.h>
#include <math.h>

#define NSIG 32768
#define KD   512
#define ED   64
#define SP   5

// ---------------- kernel A: DtD = Dt @ D + eps*I  (f64) ----------------
__global__ __launch_bounds__(256) void k_dtd(const float* __restrict__ D,
                                             double* __restrict__ DtD) {
  int flat = blockIdx.x * 256 + threadIdx.x;   // 0..262143
  int i = flat >> 9, j = flat & 511;
  double acc = 0.0;
  #pragma unroll
  for (int e = 0; e < ED; ++e)
    acc += (double)D[e * KD + i] * (double)D[e * KD + j];
  if (i == j) acc += 1e-10;
  DtD[flat] = acc;
}

// ---------------- zero the coefficients output region (float4) ----------------
__global__ __launch_bounds__(256) void k_zero(float4* __restrict__ p, size_t count4) {
  size_t i = (size_t)blockIdx.x * 256 + threadIdx.x;
  size_t stride = (size_t)gridDim.x * 256;
  float4 zv = make_float4(0.f, 0.f, 0.f, 0.f);
  for (; i < count4; i += stride) p[i] = zv;
}

// ---------------- fused kernel: corr0 compute + per-signal OMP ----------------
// Lane->atom ownership (QUAD mapping): lane li owns atoms {128*j4 + 4*li + bit},
// j4=0..3, bit=0..3; c0[4*j4+bit] holds the f64 running correlation.
// Ginv (15-entry triangle) maintained via Schur rank-1 update (1 rcp per iter).
// cc_new = Ginv*c0sel - pad(cc_old)  (reference algebra: y = c0sel - G*pad(cc_old))
template <int K>
__device__ __forceinline__ void omp_iter(const double* __restrict__ DtD,
                                         const double (&c0)[16], unsigned& amask,
                                         int (&idx)[SP], double (&cc)[SP],
                                         double (&tri)[15], double (&c0sel)[SP],
                                         int li) {
  // ----- masked corr scan over this lane's 16 atoms (4 quads) -----
  double vb = -INFINITY;
  int ab = 0x7FFFFFFF;
  #pragma unroll
  for (int j4 = 0; j4 < 4; ++j4) {
    int a0 = (j4 << 7) + (li << 2);
    double v0 = c0[4 * j4], v1 = c0[4 * j4 + 1];
    double v2 = c0[4 * j4 + 2], v3 = c0[4 * j4 + 3];
    #pragma unroll
    for (int m = 0; m < K; ++m) {
      const double* gp = DtD + (size_t)idx[m] * KD + a0;
      double2 gA = *(const double2*)gp;
      double2 gB = *(const double2*)(gp + 2);
      v0 -= gA.x * cc[m];
      v1 -= gA.y * cc[m];
      v2 -= gB.x * cc[m];
      v3 -= gB.y * cc[m];
    }
    v0 = ((amask >> (4 * j4 + 0)) & 1u) ? -INFINITY : v0;
    v1 = ((amask >> (4 * j4 + 1)) & 1u) ? -INFINITY : v1;
    v2 = ((amask >> (4 * j4 + 2)) & 1u) ? -INFINITY : v2;
    v3 = ((amask >> (4 * j4 + 3)) & 1u) ? -INFINITY : v3;
    if (v0 > vb) { vb = v0; ab = a0; }        // ascending atoms per lane:
    if (v1 > vb) { vb = v1; ab = a0 + 1; }    // strict > keeps smallest on ties
    if (v2 > vb) { vb = v2; ab = a0 + 2; }
    if (v3 > vb) { vb = v3; ab = a0 + 3; }
  }
  // ----- 32-lane group argmax, tie-break: smallest atom (matches jnp.argmax) -----
  #pragma unroll
  for (int s = 16; s >= 1; s >>= 1) {
    double ov = __shfl_xor(vb, s, 64);
    int    oa = __shfl_xor(ab, s, 64);
    if (ov > vb || (ov == vb && oa < ab)) { vb = ov; ab = oa; }
  }
  idx[K] = ab;
  if (((ab >> 2) & 31) == li) amask |= 1u << ((((ab >> 7) << 2)) | (ab & 3));
  // ----- gather new Gram row entries (symmetric: also used to rebuild c0sel) -----
  const double* drow = DtD + (size_t)ab * KD;
  double bb[SP], u[SP];
  #pragma unroll
  for (int m = 0; m < K; ++m) bb[m] = drow[idx[m]];
  // c0sel[K] = corr0[ab] = vb + sum_m DtD[ab,idx_m]*cc_m  (symmetry: = bb[m])
  {
    double csel = vb;
    #pragma unroll
    for (int m = 0; m < K; ++m) csel += bb[m] * cc[m];
    c0sel[K] = csel;
  }
  // ----- Schur rank-1 update of Ginv triangle -----
  double sch = drow[ab];
  #pragma unroll
  for (int i = 0; i < K; ++i) {
    double ui = 0.0;
    #pragma unroll
    for (int m = 0; m < K; ++m) {
      int lo = i < m ? i : m, hi = i < m ? m : i;
      ui += tri[lo * SP - lo * (lo + 1) / 2 + hi] * bb[m];
    }
    u[i] = ui;
    sch -= bb[i] * ui;
  }
  double r = 1.0 / sch;
  #pragma unroll
  for (int i = 0; i < K; ++i) {
    #pragma unroll
    for (int j = i; j < K; ++j) tri[i * SP - i * (i + 1) / 2 + j] += r * u[i] * u[j];
    tri[i * SP - i * (i + 1) / 2 + K] = -r * u[i];
  }
  tri[K * SP - K * (K + 1) / 2 + K] = r;
  // ----- h = Ginv_new * c0sel ; cc = h - pad(cc_old) -----
  double h[SP];
  #pragma unroll
  for (int i = 0; i <= K; ++i) {
    double s = 0.0;
    #pragma unroll
    for (int j = 0; j <= K; ++j) {
      int lo = i < j ? i : j, hi = i < j ? j : i;
      s += tri[lo * SP - lo * (lo + 1) / 2 + hi] * c0sel[j];
    }
    h[i] = s;
  }
  #pragma unroll
  for (int i = 0; i < K; ++i) cc[i] = h[i] - cc[i];
  cc[K] = h[K];
}

// ---- shared corr-phase: computes c0[16] for this thread's signal ----
__device__ __forceinline__ void corr_phase(const float* __restrict__ z,
                                           const float* __restrict__ D,
                                           float* __restrict__ Dlds,
                                           float* __restrict__ zbuf,
                                           int tid, int li, int mysig,
                                           int blockId, double (&c0)[16]) {
  int n = blockId * 8 + mysig;
  int b = n >> 10, p0 = (blockId * 8) & 1023;
  {
    const float* zb = z + (size_t)b * 65536 + p0;
    #pragma unroll
    for (int k2 = 0; k2 < 2; ++k2) {
      int f = tid + 256 * k2;
      zbuf[f] = zb[(f >> 3) * 1024 + (f & 7)];
    }
  }
  #pragma unroll
  for (int j = 0; j < 16; ++j) c0[j] = 0.0;
  for (int t4 = 0; t4 < 4; ++t4) {
    __syncthreads();   // protect Dlds before overwrite (also covers zbuf on t4=0)
    {
      const float4* src = (const float4*)(D + t4 * 16 * 512);
      float4* dst = (float4*)Dlds;
      #pragma unroll
      for (int i = 0; i < 8; ++i) dst[tid + 256 * i] = src[tid + 256 * i];
    }
    __syncthreads();
    #pragma unroll 4
    for (int e = 0; e < 16; ++e) {
      double zv = (double)zbuf[(t4 * 16 + e) * 8 + mysig];
      const float* drow = Dlds + e * 512;
      #pragma unroll
      for (int j4 = 0; j4 < 4; ++j4) {
        float4 dv = *(const float4*)(drow + (j4 << 7) + (li << 2));
        c0[4 * j4 + 0] += zv * (double)dv.x;
        c0[4 * j4 + 1] += zv * (double)dv.y;
        c0[4 * j4 + 2] += zv * (double)dv.z;
        c0[4 * j4 + 3] += zv * (double)dv.w;
      }
    }
  }
}

__global__ __launch_bounds__(256) void k_fused(const float* __restrict__ z,
                                               const float* __restrict__ D,
                                               const double* __restrict__ DtD,
                                               float* __restrict__ coefOut,
                                               int* __restrict__ idxWs,
                                               double* __restrict__ cWs,
                                               double* __restrict__ csumWs) {
  __shared__ float Dlds[16 * 512];   // 32 KB
  __shared__ float zbuf[64 * 8];     // 2 KB
  int tid = threadIdx.x;
  int li = tid & 31;
  int mysig = ((tid >> 6) << 1) | ((tid >> 5) & 1);   // 0..7
  int n = blockIdx.x * 8 + mysig;
  double c0[16];
  corr_phase(z, D, Dlds, zbuf, tid, li, mysig, blockIdx.x, c0);
  unsigned amask = 0;
  int idx[SP]; double cc[SP]; double tri[15]; double c0sel[SP];
  omp_iter<0>(DtD, c0, amask, idx, cc, tri, c0sel, li);
  omp_iter<1>(DtD, c0, amask, idx, cc, tri, c0sel, li);
  omp_iter<2>(DtD, c0, amask, idx, cc, tri, c0sel, li);
  omp_iter<3>(DtD, c0, amask, idx, cc, tri, c0sel, li);
  omp_iter<4>(DtD, c0, amask, idx, cc, tri, c0sel, li);
  if (li == 0) {
    double cs = 0.0;
    #pragma unroll
    for (int j = 0; j < SP; ++j) {
      double cj = cc[j];
      cj = fmin(fmax(cj, -10000000.0), 10000000.0);   // COEFF_CLAMP
      cs += fabs(cj);
      idxWs[n * SP + j] = idx[j];
      cWs[n * SP + j] = cj;
      coefOut[(size_t)idx[j] * NSIG + n] = (float)cj;
    }
    csumWs[n] = cs;
  }
}

// ---- ABLATION PROBE: corr phase only (2048 blocks = half grid) ----
// Writes nothing in practice (impossible-compare guard defeats DCE, rule 17).
__global__ __launch_bounds__(256) void k_corr_probe(const float* __restrict__ z,
                                                    const float* __restrict__ D,
                                                    double* __restrict__ probeWs) {
  __shared__ float Dlds[16 * 512];
  __shared__ float zbuf[64 * 8];
  int tid = threadIdx.x;
  int li = tid & 31;
  int mysig = ((tid >> 6) << 1) | ((tid >> 5) & 1);
  double c0[16];
  corr_phase(z, D, Dlds, zbuf, tid, li, mysig, blockIdx.x, c0);
  double s = 0.0;
  #pragma unroll
  for (int j = 0; j < 16; ++j) s += c0[j];
  if (s == 12345.6789012345) probeWs[blockIdx.x] = s;   // never true on real data
}

// ---------------- kernel D: z_q + per-block rec-loss partials ----------------
__global__ __launch_bounds__(256) void k_zq(const float* __restrict__ z,
                                            const float* __restrict__ D,
                                            const int* __restrict__ idxWs,
                                            const double* __restrict__ cWs,
                                            float* __restrict__ zqOut,
                                            double* __restrict__ recWs) {
  int t = threadIdx.x;
  size_t flat = (size_t)blockIdx.x * 256 + t;   // indexes z / z_q directly
  int b = (int)(flat >> 16);
  int e = (int)((flat >> 10) & 63);
  int p = (int)(flat & 1023);
  int n = b * 1024 + p;
  double u = 0.0;
  #pragma unroll
  for (int j = 0; j < SP; ++j) {
    int a = idxWs[n * SP + j];
    u += (double)D[e * KD + a] * cWs[n * SP + j];
  }
  float zv = z[flat];
  double d = u - (double)zv;
  double dc = fmin(fmax(d, -1.0), 1.0);
  zqOut[flat] = (float)((double)zv + dc);
  __shared__ double red[256];
  red[t] = d * d;
  __syncthreads();
  #pragma unroll
  for (int s = 128; s >= 1; s >>= 1) {
    if (t < s) red[t] += red[t + s];
    __syncthreads();
  }
  if (t == 0) recWs[blockIdx.x] = red[0];
}

// ---------------- kernel E: deterministic final reduction -> loss ----------------
__global__ __launch_bounds__(256) void k_loss(const double* __restrict__ recWs,
                                              const double* __restrict__ csumWs,
                                              float* __restrict__ lossOut) {
  int t = threadIdx.x;
  double r = 0.0, c = 0.0;
  for (int i = t; i < 8192; i += 256) r += recWs[i];
  for (int i = t; i < NSIG; i += 256) c += csumWs[i];
  __shared__ double red[512];
  red[t] = r; red[256 + t] = c;
  __syncthreads();
  #pragma unroll
  for (int s = 128; s >= 1; s >>= 1) {
    if (t < s) { red[t] += red[t + s]; red[256 + t] += red[256 + t + s]; }
    __syncthreads();
  }
  if (t == 0) {
    double rec = red[0] / (double)(64.0 * 32768.0);
    double cm  = red[256] / (double)(512.0 * 32768.0);
    // loss = rec + 0.25*(1+5/10)*commit + 1e-3*coeff ; commit == rec numerically
    double loss = rec + 0.375 * rec + 0.001 * cm;
    lossOut[0] = (float)loss;
  }
}

extern "C" void kernel_launch(void* const* d_in, const int* in_sizes, int n_in,
                              void* d_out, int out_size, void* d_ws, size_t ws_size,
                              hipStream_t stream) {
  const float* z = (const float*)d_in[0];       // (32,64,32,32)
  const float* D = (const float*)d_in[1];       // (64,512)
  float* out = (float*)d_out;
  float* zqOut   = out;                         // 2097152
  float* lossOut = out + 2097152;               // 1
  float* coefOut = out + 2097153;               // 512*32768

  // workspace carve (all 8B-aligned offsets)
  char* w = (char*)d_ws;
  double* DtD    = (double*)w; w += (size_t)KD * KD * 8;        // 2 MB
  int*    idxWs  = (int*)w;    w += (size_t)NSIG * SP * 4;      // 640 KB
  double* cWs    = (double*)w; w += (size_t)NSIG * SP * 8;      // 1.25 MB
  double* csumWs = (double*)w; w += (size_t)NSIG * 8;           // 256 KB
  double* recWs  = (double*)w; w += (size_t)8192 * 8;           // 64 KB
  double* probeWs = (double*)w; w += (size_t)4096 * 8;          // 32 KB

  k_dtd<<<1024, 256, 0, stream>>>(D, DtD);
  k_zero<<<2048, 256, 0, stream>>>((float4*)coefOut, (size_t)KD * NSIG / 4);
  k_fused<<<NSIG / 8, 256, 0, stream>>>(z, D, DtD, coefOut, idxWs, cWs, csumWs);
  k_zq<<<8192, 256, 0, stream>>>(z, D, idxWs, cWs, zqOut, recWs);
  k_loss<<<1, 256, 0, stream>>>(recWs, csumWs, lossOut);
  // ablation probe: corr-phase-only timing at half grid (read dur via rocprof)
  k_corr_probe<<<2048, 256, 0, stream>>>(z, D, probeWs);
}

// Round 7
// 229.286 us; speedup vs baseline: 1.1484x; 1.1484x over previous
//
#include <hip/hip_runtime.h>
#include <math.h>

#define NSIG 32768
#define KD   512
#define ED   64
#define SP   5

// ---------------- kernel A: DtD = Dt @ D + eps*I  (f64) ----------------
__global__ __launch_bounds__(256) void k_dtd(const float* __restrict__ D,
                                             double* __restrict__ DtD) {
  int flat = blockIdx.x * 256 + threadIdx.x;   // 0..262143
  int i = flat >> 9, j = flat & 511;
  double acc = 0.0;
  #pragma unroll
  for (int e = 0; e < ED; ++e)
    acc += (double)D[e * KD + i] * (double)D[e * KD + j];
  if (i == j) acc += 1e-10;
  DtD[flat] = acc;
}

// ---------------- zero the coefficients output region (float4) ----------------
__global__ __launch_bounds__(256) void k_zero(float4* __restrict__ p, size_t count4) {
  size_t i = (size_t)blockIdx.x * 256 + threadIdx.x;
  size_t stride = (size_t)gridDim.x * 256;
  float4 zv = make_float4(0.f, 0.f, 0.f, 0.f);
  for (; i < count4; i += stride) p[i] = zv;
}

// ---------------- fused kernel: corr0 compute + per-signal OMP ----------------
// CORR layout: lane l (0..63) owns atoms {8l..8l+7}; accumulates BOTH of the
//   wave's signals (cA = sig 2w, cB = sig 2w+1) -> D LDS reads shared 2x.
// SCAN layout (omp_iter, unchanged): 32-lane group g handles signal 2w+g;
//   lane li owns atoms {128*j4 + 4*li + bit}. One-time shuffle exchange maps
//   corr->scan: src lane = 16*j4 + (li>>1), pos = 4*(li&1)+bit (static regs).
// Ginv (15-entry triangle) maintained via Schur rank-1 update (1 rcp per iter).
// cc_new = Ginv*c0sel - pad(cc_old)  (reference algebra: y = c0sel - G*pad(cc_old))
template <int K>
__device__ __forceinline__ void omp_iter(const double* __restrict__ DtD,
                                         const double (&c0)[16], unsigned& amask,
                                         int (&idx)[SP], double (&cc)[SP],
                                         double (&tri)[15], double (&c0sel)[SP],
                                         int li) {
  // ----- masked corr scan over this lane's 16 atoms (4 quads) -----
  double vb = -INFINITY;
  int ab = 0x7FFFFFFF;
  #pragma unroll
  for (int j4 = 0; j4 < 4; ++j4) {
    int a0 = (j4 << 7) + (li << 2);
    double v0 = c0[4 * j4], v1 = c0[4 * j4 + 1];
    double v2 = c0[4 * j4 + 2], v3 = c0[4 * j4 + 3];
    #pragma unroll
    for (int m = 0; m < K; ++m) {
      const double* gp = DtD + (size_t)idx[m] * KD + a0;
      double2 gA = *(const double2*)gp;
      double2 gB = *(const double2*)(gp + 2);
      v0 -= gA.x * cc[m];
      v1 -= gA.y * cc[m];
      v2 -= gB.x * cc[m];
      v3 -= gB.y * cc[m];
    }
    v0 = ((amask >> (4 * j4 + 0)) & 1u) ? -INFINITY : v0;
    v1 = ((amask >> (4 * j4 + 1)) & 1u) ? -INFINITY : v1;
    v2 = ((amask >> (4 * j4 + 2)) & 1u) ? -INFINITY : v2;
    v3 = ((amask >> (4 * j4 + 3)) & 1u) ? -INFINITY : v3;
    if (v0 > vb) { vb = v0; ab = a0; }        // ascending atoms per lane:
    if (v1 > vb) { vb = v1; ab = a0 + 1; }    // strict > keeps smallest on ties
    if (v2 > vb) { vb = v2; ab = a0 + 2; }
    if (v3 > vb) { vb = v3; ab = a0 + 3; }
  }
  // ----- 32-lane group argmax, tie-break: smallest atom (matches jnp.argmax) -----
  #pragma unroll
  for (int s = 16; s >= 1; s >>= 1) {
    double ov = __shfl_xor(vb, s, 64);
    int    oa = __shfl_xor(ab, s, 64);
    if (ov > vb || (ov == vb && oa < ab)) { vb = ov; ab = oa; }
  }
  idx[K] = ab;
  if (((ab >> 2) & 31) == li) amask |= 1u << ((((ab >> 7) << 2)) | (ab & 3));
  // ----- gather new Gram row entries (symmetric: also used to rebuild c0sel) -----
  const double* drow = DtD + (size_t)ab * KD;
  double bb[SP], u[SP];
  #pragma unroll
  for (int m = 0; m < K; ++m) bb[m] = drow[idx[m]];
  // c0sel[K] = corr0[ab] = vb + sum_m DtD[ab,idx_m]*cc_m  (symmetry: = bb[m])
  {
    double csel = vb;
    #pragma unroll
    for (int m = 0; m < K; ++m) csel += bb[m] * cc[m];
    c0sel[K] = csel;
  }
  // ----- Schur rank-1 update of Ginv triangle -----
  double sch = drow[ab];
  #pragma unroll
  for (int i = 0; i < K; ++i) {
    double ui = 0.0;
    #pragma unroll
    for (int m = 0; m < K; ++m) {
      int lo = i < m ? i : m, hi = i < m ? m : i;
      ui += tri[lo * SP - lo * (lo + 1) / 2 + hi] * bb[m];
    }
    u[i] = ui;
    sch -= bb[i] * ui;
  }
  double r = 1.0 / sch;
  #pragma unroll
  for (int i = 0; i < K; ++i) {
    #pragma unroll
    for (int j = i; j < K; ++j) tri[i * SP - i * (i + 1) / 2 + j] += r * u[i] * u[j];
    tri[i * SP - i * (i + 1) / 2 + K] = -r * u[i];
  }
  tri[K * SP - K * (K + 1) / 2 + K] = r;
  // ----- h = Ginv_new * c0sel ; cc = h - pad(cc_old) -----
  double h[SP];
  #pragma unroll
  for (int i = 0; i <= K; ++i) {
    double s = 0.0;
    #pragma unroll
    for (int j = 0; j <= K; ++j) {
      int lo = i < j ? i : j, hi = i < j ? j : i;
      s += tri[lo * SP - lo * (lo + 1) / 2 + hi] * c0sel[j];
    }
    h[i] = s;
  }
  #pragma unroll
  for (int i = 0; i < K; ++i) cc[i] = h[i] - cc[i];
  cc[K] = h[K];
}

__global__ __launch_bounds__(256) void k_fused(const float* __restrict__ z,
                                               const float* __restrict__ D,
                                               const double* __restrict__ DtD,
                                               float* __restrict__ coefOut,
                                               int* __restrict__ idxWs,
                                               double* __restrict__ cWs,
                                               double* __restrict__ csumWs) {
  __shared__ float Dlds[16 * 512];   // 32 KB: one 16-row tile of D
  __shared__ float zbuf[64 * 8];     // 2 KB: [e][sig] for the block's 8 signals
  int tid = threadIdx.x;
  int lane = tid & 63;
  int wv = tid >> 6;                 // wave id 0..3 -> signals 2wv, 2wv+1
  int li = lane & 31;
  int g  = lane >> 5;                // scan group: signal 2wv+g
  int n = blockIdx.x * 8 + 2 * wv + g;
  // ---- stage z: zbuf[e*8+sig] = z[b, e, p0+sig] ----
  {
    int n0 = blockIdx.x * 8;
    int b = n0 >> 10, p0 = n0 & 1023;
    const float* zb = z + (size_t)b * 65536 + p0;
    #pragma unroll
    for (int k2 = 0; k2 < 2; ++k2) {
      int f = tid + 256 * k2;
      zbuf[f] = zb[(f >> 3) * 1024 + (f & 7)];
    }
  }
  // ---- corr phase: lane owns atoms 8*lane..8*lane+7, both wave signals ----
  double cA[8], cB[8];
  #pragma unroll
  for (int p = 0; p < 8; ++p) { cA[p] = 0.0; cB[p] = 0.0; }
  for (int t4 = 0; t4 < 4; ++t4) {
    __syncthreads();   // protect Dlds before overwrite (also covers zbuf on t4=0)
    {
      const float4* src = (const float4*)(D + t4 * 16 * 512);
      float4* dst = (float4*)Dlds;
      #pragma unroll
      for (int i = 0; i < 8; ++i) dst[tid + 256 * i] = src[tid + 256 * i];
    }
    __syncthreads();
    #pragma unroll 4
    for (int e = 0; e < 16; ++e) {
      float2 zz = *(const float2*)(zbuf + (t4 * 16 + e) * 8 + 2 * wv);
      double zA = (double)zz.x, zB = (double)zz.y;
      const float* dp = Dlds + e * 512 + lane * 8;
      float4 d0 = *(const float4*)dp;
      float4 d1 = *(const float4*)(dp + 4);
      double dv[8] = {(double)d0.x, (double)d0.y, (double)d0.z, (double)d0.w,
                      (double)d1.x, (double)d1.y, (double)d1.z, (double)d1.w};
      #pragma unroll
      for (int p = 0; p < 8; ++p) {
        cA[p] += zA * dv[p];
        cB[p] += zB * dv[p];
      }
    }
  }
  // ---- exchange corr layout -> scan layout (bit-identical values) ----
  // scan c0[4*j4+bit] = corr(atom 128*j4+4*li+bit, signal 2wv+g)
  //   = (g? cB : cA)[4*(li&1)+bit] held by lane 16*j4+(li>>1)
  double c0[16];
  {
    int odd = li & 1;
    #pragma unroll
    for (int j4 = 0; j4 < 4; ++j4) {
      int src = 16 * j4 + (li >> 1);
      #pragma unroll
      for (int bit = 0; bit < 4; ++bit) {
        double tA0 = __shfl(cA[bit], src, 64);
        double tA1 = __shfl(cA[4 + bit], src, 64);
        double tB0 = __shfl(cB[bit], src, 64);
        double tB1 = __shfl(cB[4 + bit], src, 64);
        double vA = odd ? tA1 : tA0;
        double vB = odd ? tB1 : tB0;
        c0[4 * j4 + bit] = g ? vB : vA;
      }
    }
  }
  // ---- OMP iterations (scan layout unchanged) ----
  unsigned amask = 0;
  int idx[SP]; double cc[SP]; double tri[15]; double c0sel[SP];
  omp_iter<0>(DtD, c0, amask, idx, cc, tri, c0sel, li);
  omp_iter<1>(DtD, c0, amask, idx, cc, tri, c0sel, li);
  omp_iter<2>(DtD, c0, amask, idx, cc, tri, c0sel, li);
  omp_iter<3>(DtD, c0, amask, idx, cc, tri, c0sel, li);
  omp_iter<4>(DtD, c0, amask, idx, cc, tri, c0sel, li);
  if (li == 0) {
    double cs = 0.0;
    #pragma unroll
    for (int j = 0; j < SP; ++j) {
      double cj = cc[j];
      cj = fmin(fmax(cj, -10000000.0), 10000000.0);   // COEFF_CLAMP
      cs += fabs(cj);
      idxWs[n * SP + j] = idx[j];
      cWs[n * SP + j] = cj;
      coefOut[(size_t)idx[j] * NSIG + n] = (float)cj;
    }
    csumWs[n] = cs;
  }
}

// ---------------- kernel D: z_q + per-block rec-loss partials ----------------
__global__ __launch_bounds__(256) void k_zq(const float* __restrict__ z,
                                            const float* __restrict__ D,
                                            const int* __restrict__ idxWs,
                                            const double* __restrict__ cWs,
                                            float* __restrict__ zqOut,
                                            double* __restrict__ recWs) {
  int t = threadIdx.x;
  size_t flat = (size_t)blockIdx.x * 256 + t;   // indexes z / z_q directly
  int b = (int)(flat >> 16);
  int e = (int)((flat >> 10) & 63);
  int p = (int)(flat & 1023);
  int n = b * 1024 + p;
  double u = 0.0;
  #pragma unroll
  for (int j = 0; j < SP; ++j) {
    int a = idxWs[n * SP + j];
    u += (double)D[e * KD + a] * cWs[n * SP + j];
  }
  float zv = z[flat];
  double d = u - (double)zv;
  double dc = fmin(fmax(d, -1.0), 1.0);
  zqOut[flat] = (float)((double)zv + dc);
  __shared__ double red[256];
  red[t] = d * d;
  __syncthreads();
  #pragma unroll
  for (int s = 128; s >= 1; s >>= 1) {
    if (t < s) red[t] += red[t + s];
    __syncthreads();
  }
  if (t == 0) recWs[blockIdx.x] = red[0];
}

// ---------------- kernel E: deterministic final reduction -> loss ----------------
__global__ __launch_bounds__(256) void k_loss(const double* __restrict__ recWs,
                                              const double* __restrict__ csumWs,
                                              float* __restrict__ lossOut) {
  int t = threadIdx.x;
  double r = 0.0, c = 0.0;
  for (int i = t; i < 8192; i += 256) r += recWs[i];
  for (int i = t; i < NSIG; i += 256) c += csumWs[i];
  __shared__ double red[512];
  red[t] = r; red[256 + t] = c;
  __syncthreads();
  #pragma unroll
  for (int s = 128; s >= 1; s >>= 1) {
    if (t < s) { red[t] += red[t + s]; red[256 + t] += red[256 + t + s]; }
    __syncthreads();
  }
  if (t == 0) {
    double rec = red[0] / (double)(64.0 * 32768.0);
    double cm  = red[256] / (double)(512.0 * 32768.0);
    // loss = rec + 0.25*(1+5/10)*commit + 1e-3*coeff ; commit == rec numerically
    double loss = rec + 0.375 * rec + 0.001 * cm;
    lossOut[0] = (float)loss;
  }
}

extern "C" void kernel_launch(void* const* d_in, const int* in_sizes, int n_in,
                              void* d_out, int out_size, void* d_ws, size_t ws_size,
                              hipStream_t stream) {
  const float* z = (const float*)d_in[0];       // (32,64,32,32)
  const float* D = (const float*)d_in[1];       // (64,512)
  float* out = (float*)d_out;
  float* zqOut   = out;                         // 2097152
  float* lossOut = out + 2097152;               // 1
  float* coefOut = out + 2097153;               // 512*32768

  // workspace carve (all 8B-aligned offsets)
  char* w = (char*)d_ws;
  double* DtD    = (double*)w; w += (size_t)KD * KD * 8;        // 2 MB
  int*    idxWs  = (int*)w;    w += (size_t)NSIG * SP * 4;      // 640 KB
  double* cWs    = (double*)w; w += (size_t)NSIG * SP * 8;      // 1.25 MB
  double* csumWs = (double*)w; w += (size_t)NSIG * 8;           // 256 KB
  double* recWs  = (double*)w; w += (size_t)8192 * 8;           // 64 KB

  k_dtd<<<1024, 256, 0, stream>>>(D, DtD);
  k_zero<<<2048, 256, 0, stream>>>((float4*)coefOut, (size_t)KD * NSIG / 4);
  k_fused<<<NSIG / 8, 256, 0, stream>>>(z, D, DtD, coefOut, idxWs, cWs, csumWs);
  k_zq<<<8192, 256, 0, stream>>>(z, D, idxWs, cWs, zqOut, recWs);
  k_loss<<<1, 256, 0, stream>>>(recWs, csumWs, lossOut);
}

// Round 8
// 220.377 us; speedup vs baseline: 1.1948x; 1.0404x over previous
//
#include <hip/hip_runtime.h>
#include <math.h>

#define NSIG 32768
#define KD   512
#define ED   64
#define SP   5

// ---------------- kernel A: DtD = Dt @ D + eps*I  (f64) ----------------
__global__ __launch_bounds__(256) void k_dtd(const float* __restrict__ D,
                                             double* __restrict__ DtD) {
  int flat = blockIdx.x * 256 + threadIdx.x;   // 0..262143
  int i = flat >> 9, j = flat & 511;
  double acc = 0.0;
  #pragma unroll
  for (int e = 0; e < ED; ++e)
    acc += (double)D[e * KD + i] * (double)D[e * KD + j];
  if (i == j) acc += 1e-10;
  DtD[flat] = acc;
}

// ---------------- zero the coefficients output region (float4) ----------------
__global__ __launch_bounds__(256) void k_zero(float4* __restrict__ p, size_t count4) {
  size_t i = (size_t)blockIdx.x * 256 + threadIdx.x;
  size_t stride = (size_t)gridDim.x * 256;
  float4 zv = make_float4(0.f, 0.f, 0.f, 0.f);
  for (; i < count4; i += stride) p[i] = zv;
}

// ---------------- fused kernel: corr0 compute + per-signal OMP ----------------
// CORR layout: lane l (0..63) owns atoms {4l..4l+3} U {256+4l..256+4l+3};
//   accumulates BOTH wave signals (cA = sig 2wv, cB = sig 2wv+1).
//   Per e-row: two float4 LDS reads at byte offsets l*16 and 1024+l*16 —
//   contiguous 16B-stride (the zero-conflict class measured in R5/R6).
// SCAN layout (omp_iter, unchanged): 32-lane group g handles signal 2wv+g;
//   lane li owns atoms {128*j4 + 4*li + bit}. Exchange (derived):
//   c0[4*j4+bit] = (g? cB:cA)[4*(j4>>1)+bit] from lane 32*(j4&1)+li.
// Ginv (15-entry triangle) maintained via Schur rank-1 update (1 rcp per iter).
// cc_new = Ginv*c0sel - pad(cc_old)  (reference algebra: y = c0sel - G*pad(cc_old))
template <int K>
__device__ __forceinline__ void omp_iter(const double* __restrict__ DtD,
                                         const double (&c0)[16], unsigned& amask,
                                         int (&idx)[SP], double (&cc)[SP],
                                         double (&tri)[15], double (&c0sel)[SP],
                                         int li) {
  // ----- masked corr scan over this lane's 16 atoms (4 quads) -----
  double vb = -INFINITY;
  int ab = 0x7FFFFFFF;
  #pragma unroll
  for (int j4 = 0; j4 < 4; ++j4) {
    int a0 = (j4 << 7) + (li << 2);
    double v0 = c0[4 * j4], v1 = c0[4 * j4 + 1];
    double v2 = c0[4 * j4 + 2], v3 = c0[4 * j4 + 3];
    #pragma unroll
    for (int m = 0; m < K; ++m) {
      const double* gp = DtD + (size_t)idx[m] * KD + a0;
      double2 gA = *(const double2*)gp;
      double2 gB = *(const double2*)(gp + 2);
      v0 -= gA.x * cc[m];
      v1 -= gA.y * cc[m];
      v2 -= gB.x * cc[m];
      v3 -= gB.y * cc[m];
    }
    v0 = ((amask >> (4 * j4 + 0)) & 1u) ? -INFINITY : v0;
    v1 = ((amask >> (4 * j4 + 1)) & 1u) ? -INFINITY : v1;
    v2 = ((amask >> (4 * j4 + 2)) & 1u) ? -INFINITY : v2;
    v3 = ((amask >> (4 * j4 + 3)) & 1u) ? -INFINITY : v3;
    if (v0 > vb) { vb = v0; ab = a0; }        // ascending atoms per lane:
    if (v1 > vb) { vb = v1; ab = a0 + 1; }    // strict > keeps smallest on ties
    if (v2 > vb) { vb = v2; ab = a0 + 2; }
    if (v3 > vb) { vb = v3; ab = a0 + 3; }
  }
  // ----- 32-lane group argmax, tie-break: smallest atom (matches jnp.argmax) -----
  #pragma unroll
  for (int s = 16; s >= 1; s >>= 1) {
    double ov = __shfl_xor(vb, s, 64);
    int    oa = __shfl_xor(ab, s, 64);
    if (ov > vb || (ov == vb && oa < ab)) { vb = ov; ab = oa; }
  }
  idx[K] = ab;
  if (((ab >> 2) & 31) == li) amask |= 1u << ((((ab >> 7) << 2)) | (ab & 3));
  // ----- gather new Gram row entries (symmetric: also used to rebuild c0sel) -----
  const double* drow = DtD + (size_t)ab * KD;
  double bb[SP], u[SP];
  #pragma unroll
  for (int m = 0; m < K; ++m) bb[m] = drow[idx[m]];
  // c0sel[K] = corr0[ab] = vb + sum_m DtD[ab,idx_m]*cc_m  (symmetry: = bb[m])
  {
    double csel = vb;
    #pragma unroll
    for (int m = 0; m < K; ++m) csel += bb[m] * cc[m];
    c0sel[K] = csel;
  }
  // ----- Schur rank-1 update of Ginv triangle -----
  double sch = drow[ab];
  #pragma unroll
  for (int i = 0; i < K; ++i) {
    double ui = 0.0;
    #pragma unroll
    for (int m = 0; m < K; ++m) {
      int lo = i < m ? i : m, hi = i < m ? m : i;
      ui += tri[lo * SP - lo * (lo + 1) / 2 + hi] * bb[m];
    }
    u[i] = ui;
    sch -= bb[i] * ui;
  }
  double r = 1.0 / sch;
  #pragma unroll
  for (int i = 0; i < K; ++i) {
    #pragma unroll
    for (int j = i; j < K; ++j) tri[i * SP - i * (i + 1) / 2 + j] += r * u[i] * u[j];
    tri[i * SP - i * (i + 1) / 2 + K] = -r * u[i];
  }
  tri[K * SP - K * (K + 1) / 2 + K] = r;
  // ----- h = Ginv_new * c0sel ; cc = h - pad(cc_old) -----
  double h[SP];
  #pragma unroll
  for (int i = 0; i <= K; ++i) {
    double s = 0.0;
    #pragma unroll
    for (int j = 0; j <= K; ++j) {
      int lo = i < j ? i : j, hi = i < j ? j : i;
      s += tri[lo * SP - lo * (lo + 1) / 2 + hi] * c0sel[j];
    }
    h[i] = s;
  }
  #pragma unroll
  for (int i = 0; i < K; ++i) cc[i] = h[i] - cc[i];
  cc[K] = h[K];
}

__global__ __launch_bounds__(256) void k_fused(const float* __restrict__ z,
                                               const float* __restrict__ D,
                                               const double* __restrict__ DtD,
                                               float* __restrict__ coefOut,
                                               int* __restrict__ idxWs,
                                               double* __restrict__ cWs,
                                               double* __restrict__ csumWs) {
  __shared__ float Dlds[16 * 512];   // 32 KB: one 16-row tile of D
  __shared__ float zbuf[64 * 8];     // 2 KB: [e][sig] for the block's 8 signals
  int tid = threadIdx.x;
  int lane = tid & 63;
  int wv = tid >> 6;                 // wave id 0..3 -> signals 2wv, 2wv+1
  int li = lane & 31;
  int g  = lane >> 5;                // scan group: signal 2wv+g
  int n = blockIdx.x * 8 + 2 * wv + g;
  // ---- stage z: zbuf[e*8+sig] = z[b, e, p0+sig] ----
  {
    int n0 = blockIdx.x * 8;
    int b = n0 >> 10, p0 = n0 & 1023;
    const float* zb = z + (size_t)b * 65536 + p0;
    #pragma unroll
    for (int k2 = 0; k2 < 2; ++k2) {
      int f = tid + 256 * k2;
      zbuf[f] = zb[(f >> 3) * 1024 + (f & 7)];
    }
  }
  // ---- corr phase: lane owns atoms {4l..4l+3} U {256+4l..+3}, both signals ----
  double cA[8], cB[8];
  #pragma unroll
  for (int p = 0; p < 8; ++p) { cA[p] = 0.0; cB[p] = 0.0; }
  for (int t4 = 0; t4 < 4; ++t4) {
    __syncthreads();   // protect Dlds before overwrite (also covers zbuf on t4=0)
    {
      const float4* src = (const float4*)(D + t4 * 16 * 512);
      float4* dst = (float4*)Dlds;
      #pragma unroll
      for (int i = 0; i < 8; ++i) dst[tid + 256 * i] = src[tid + 256 * i];
    }
    __syncthreads();
    #pragma unroll 4
    for (int e = 0; e < 16; ++e) {
      float2 zz = *(const float2*)(zbuf + (t4 * 16 + e) * 8 + 2 * wv);
      double zA = (double)zz.x, zB = (double)zz.y;
      const float* drow = Dlds + e * 512;
      float4 d0 = *(const float4*)(drow + lane * 4);         // atoms 4l..4l+3
      float4 d1 = *(const float4*)(drow + 256 + lane * 4);   // atoms 256+4l..+3
      double dv[8] = {(double)d0.x, (double)d0.y, (double)d0.z, (double)d0.w,
                      (double)d1.x, (double)d1.y, (double)d1.z, (double)d1.w};
      #pragma unroll
      for (int p = 0; p < 8; ++p) {
        cA[p] += zA * dv[p];
        cB[p] += zB * dv[p];
      }
    }
  }
  // ---- exchange corr layout -> scan layout (bit-identical values) ----
  // c0[4*j4+bit] = (g? cB:cA)[4*(j4>>1)+bit] held by lane 32*(j4&1)+li
  double c0[16];
  #pragma unroll
  for (int j4 = 0; j4 < 4; ++j4) {
    int src = ((j4 & 1) << 5) + li;
    #pragma unroll
    for (int bit = 0; bit < 4; ++bit) {
      double tA = __shfl(cA[((j4 >> 1) << 2) + bit], src, 64);
      double tB = __shfl(cB[((j4 >> 1) << 2) + bit], src, 64);
      c0[4 * j4 + bit] = g ? tB : tA;
    }
  }
  // ---- OMP iterations (scan layout unchanged) ----
  unsigned amask = 0;
  int idx[SP]; double cc[SP]; double tri[15]; double c0sel[SP];
  omp_iter<0>(DtD, c0, amask, idx, cc, tri, c0sel, li);
  omp_iter<1>(DtD, c0, amask, idx, cc, tri, c0sel, li);
  omp_iter<2>(DtD, c0, amask, idx, cc, tri, c0sel, li);
  omp_iter<3>(DtD, c0, amask, idx, cc, tri, c0sel, li);
  omp_iter<4>(DtD, c0, amask, idx, cc, tri, c0sel, li);
  if (li == 0) {
    double cs = 0.0;
    #pragma unroll
    for (int j = 0; j < SP; ++j) {
      double cj = cc[j];
      cj = fmin(fmax(cj, -10000000.0), 10000000.0);   // COEFF_CLAMP
      cs += fabs(cj);
      idxWs[n * SP + j] = idx[j];
      cWs[n * SP + j] = cj;
      coefOut[(size_t)idx[j] * NSIG + n] = (float)cj;
    }
    csumWs[n] = cs;
  }
}

// ---------------- kernel D: z_q + per-block rec-loss partials ----------------
__global__ __launch_bounds__(256) void k_zq(const float* __restrict__ z,
                                            const float* __restrict__ D,
                                            const int* __restrict__ idxWs,
                                            const double* __restrict__ cWs,
                                            float* __restrict__ zqOut,
                                            double* __restrict__ recWs) {
  int t = threadIdx.x;
  size_t flat = (size_t)blockIdx.x * 256 + t;   // indexes z / z_q directly
  int b = (int)(flat >> 16);
  int e = (int)((flat >> 10) & 63);
  int p = (int)(flat & 1023);
  int n = b * 1024 + p;
  double u = 0.0;
  #pragma unroll
  for (int j = 0; j < SP; ++j) {
    int a = idxWs[n * SP + j];
    u += (double)D[e * KD + a] * cWs[n * SP + j];
  }
  float zv = z[flat];
  double d = u - (double)zv;
  double dc = fmin(fmax(d, -1.0), 1.0);
  zqOut[flat] = (float)((double)zv + dc);
  __shared__ double red[256];
  red[t] = d * d;
  __syncthreads();
  #pragma unroll
  for (int s = 128; s >= 1; s >>= 1) {
    if (t < s) red[t] += red[t + s];
    __syncthreads();
  }
  if (t == 0) recWs[blockIdx.x] = red[0];
}

// ---------------- kernel E: deterministic final reduction -> loss ----------------
__global__ __launch_bounds__(256) void k_loss(const double* __restrict__ recWs,
                                              const double* __restrict__ csumWs,
                                              float* __restrict__ lossOut) {
  int t = threadIdx.x;
  double r = 0.0, c = 0.0;
  for (int i = t; i < 8192; i += 256) r += recWs[i];
  for (int i = t; i < NSIG; i += 256) c += csumWs[i];
  __shared__ double red[512];
  red[t] = r; red[256 + t] = c;
  __syncthreads();
  #pragma unroll
  for (int s = 128; s >= 1; s >>= 1) {
    if (t < s) { red[t] += red[t + s]; red[256 + t] += red[256 + t + s]; }
    __syncthreads();
  }
  if (t == 0) {
    double rec = red[0] / (double)(64.0 * 32768.0);
    double cm  = red[256] / (double)(512.0 * 32768.0);
    // loss = rec + 0.25*(1+5/10)*commit + 1e-3*coeff ; commit == rec numerically
    double loss = rec + 0.375 * rec + 0.001 * cm;
    lossOut[0] = (float)loss;
  }
}

extern "C" void kernel_launch(void* const* d_in, const int* in_sizes, int n_in,
                              void* d_out, int out_size, void* d_ws, size_t ws_size,
                              hipStream_t stream) {
  const float* z = (const float*)d_in[0];       // (32,64,32,32)
  const float* D = (const float*)d_in[1];       // (64,512)
  float* out = (float*)d_out;
  float* zqOut   = out;                         // 2097152
  float* lossOut = out + 2097152;               // 1
  float* coefOut = out + 2097153;               // 512*32768

  // workspace carve (all 8B-aligned offsets)
  char* w = (char*)d_ws;
  double* DtD    = (double*)w; w += (size_t)KD * KD * 8;        // 2 MB
  int*    idxWs  = (int*)w;    w += (size_t)NSIG * SP * 4;      // 640 KB
  double* cWs    = (double*)w; w += (size_t)NSIG * SP * 8;      // 1.25 MB
  double* csumWs = (double*)w; w += (size_t)NSIG * 8;           // 256 KB
  double* recWs  = (double*)w; w += (size_t)8192 * 8;           // 64 KB

  k_dtd<<<1024, 256, 0, stream>>>(D, DtD);
  k_zero<<<2048, 256, 0, stream>>>((float4*)coefOut, (size_t)KD * NSIG / 4);
  k_fused<<<NSIG / 8, 256, 0, stream>>>(z, D, DtD, coefOut, idxWs, cWs, csumWs);
  k_zq<<<8192, 256, 0, stream>>>(z, D, idxWs, cWs, zqOut, recWs);
  k_loss<<<1, 256, 0, stream>>>(recWs, csumWs, lossOut);
}

// Round 9
// 218.028 us; speedup vs baseline: 1.2076x; 1.0108x over previous
//
#include <hip/hip_runtime.h>
#include <math.h>

#define NSIG 32768
#define KD   512
#define ED   64
#define SP   5

// ---------------- prologue: DtD = Dt@D + eps*I  AND  zero coefOut ----------------
__global__ __launch_bounds__(256) void k_pre(const float* __restrict__ D,
                                             double* __restrict__ DtD,
                                             float4* __restrict__ coef4) {
  if (blockIdx.x < 1024) {
    int flat = blockIdx.x * 256 + threadIdx.x;   // 0..262143
    int i = flat >> 9, j = flat & 511;
    double acc = 0.0;
    #pragma unroll
    for (int e = 0; e < ED; ++e)
      acc += (double)D[e * KD + i] * (double)D[e * KD + j];
    if (i == j) acc += 1e-10;
    DtD[flat] = acc;
  } else {
    size_t count4 = (size_t)KD * NSIG / 4;
    size_t i = (size_t)(blockIdx.x - 1024) * 256 + threadIdx.x;
    size_t stride = (size_t)2048 * 256;
    float4 zv = make_float4(0.f, 0.f, 0.f, 0.f);
    for (; i < count4; i += stride) coef4[i] = zv;
  }
}

// ---------------- fused kernel: corr0 compute + per-signal OMP ----------------
// CORR layout: lane l (0..63) owns atoms {4l..4l+3} U {256+4l..256+4l+3};
//   accumulates BOTH wave signals (cA = sig 2wv, cB = sig 2wv+1).
//   Per e-row: two float4 LDS reads at byte offsets l*16 and 1024+l*16 —
//   contiguous 16B-stride (zero-conflict class, verified R8: SQ_LDS_BANK_CONFLICT=0).
// SCAN layout (omp_iter, unchanged): 32-lane group g handles signal 2wv+g;
//   lane li owns atoms {128*j4 + 4*li + bit}. Exchange:
//   c0[4*j4+bit] = (g? cB:cA)[4*(j4>>1)+bit] from lane 32*(j4&1)+li.
// Ginv (15-entry triangle) via Schur rank-1 update (1 rcp per iter).
// cc_new = Ginv*c0sel - pad(cc_old)  (reference algebra: y = c0sel - G*pad(cc_old))
template <int K>
__device__ __forceinline__ void omp_iter(const double* __restrict__ DtD,
                                         const double (&c0)[16], unsigned& amask,
                                         int (&idx)[SP], double (&cc)[SP],
                                         double (&tri)[15], double (&c0sel)[SP],
                                         int li) {
  // ----- masked corr scan over this lane's 16 atoms (4 quads) -----
  double vb = -INFINITY;
  int ab = 0x7FFFFFFF;
  #pragma unroll
  for (int j4 = 0; j4 < 4; ++j4) {
    int a0 = (j4 << 7) + (li << 2);
    double v0 = c0[4 * j4], v1 = c0[4 * j4 + 1];
    double v2 = c0[4 * j4 + 2], v3 = c0[4 * j4 + 3];
    #pragma unroll
    for (int m = 0; m < K; ++m) {
      const double* gp = DtD + (size_t)idx[m] * KD + a0;
      double2 gA = *(const double2*)gp;
      double2 gB = *(const double2*)(gp + 2);
      v0 -= gA.x * cc[m];
      v1 -= gA.y * cc[m];
      v2 -= gB.x * cc[m];
      v3 -= gB.y * cc[m];
    }
    v0 = ((amask >> (4 * j4 + 0)) & 1u) ? -INFINITY : v0;
    v1 = ((amask >> (4 * j4 + 1)) & 1u) ? -INFINITY : v1;
    v2 = ((amask >> (4 * j4 + 2)) & 1u) ? -INFINITY : v2;
    v3 = ((amask >> (4 * j4 + 3)) & 1u) ? -INFINITY : v3;
    if (v0 > vb) { vb = v0; ab = a0; }        // ascending atoms per lane:
    if (v1 > vb) { vb = v1; ab = a0 + 1; }    // strict > keeps smallest on ties
    if (v2 > vb) { vb = v2; ab = a0 + 2; }
    if (v3 > vb) { vb = v3; ab = a0 + 3; }
  }
  // ----- 32-lane group argmax, tie-break: smallest atom (matches jnp.argmax) -----
  #pragma unroll
  for (int s = 16; s >= 1; s >>= 1) {
    double ov = __shfl_xor(vb, s, 64);
    int    oa = __shfl_xor(ab, s, 64);
    if (ov > vb || (ov == vb && oa < ab)) { vb = ov; ab = oa; }
  }
  idx[K] = ab;
  if (((ab >> 2) & 31) == li) amask |= 1u << ((((ab >> 7) << 2)) | (ab & 3));
  // ----- gather new Gram row entries (symmetric: also used to rebuild c0sel) -----
  const double* drow = DtD + (size_t)ab * KD;
  double bb[SP], u[SP];
  #pragma unroll
  for (int m = 0; m < K; ++m) bb[m] = drow[idx[m]];
  // c0sel[K] = corr0[ab] = vb + sum_m DtD[ab,idx_m]*cc_m  (symmetry: = bb[m])
  {
    double csel = vb;
    #pragma unroll
    for (int m = 0; m < K; ++m) csel += bb[m] * cc[m];
    c0sel[K] = csel;
  }
  // ----- Schur rank-1 update of Ginv triangle -----
  double sch = drow[ab];
  #pragma unroll
  for (int i = 0; i < K; ++i) {
    double ui = 0.0;
    #pragma unroll
    for (int m = 0; m < K; ++m) {
      int lo = i < m ? i : m, hi = i < m ? m : i;
      ui += tri[lo * SP - lo * (lo + 1) / 2 + hi] * bb[m];
    }
    u[i] = ui;
    sch -= bb[i] * ui;
  }
  double r = 1.0 / sch;
  #pragma unroll
  for (int i = 0; i < K; ++i) {
    #pragma unroll
    for (int j = i; j < K; ++j) tri[i * SP - i * (i + 1) / 2 + j] += r * u[i] * u[j];
    tri[i * SP - i * (i + 1) / 2 + K] = -r * u[i];
  }
  tri[K * SP - K * (K + 1) / 2 + K] = r;
  // ----- h = Ginv_new * c0sel ; cc = h - pad(cc_old) -----
  double h[SP];
  #pragma unroll
  for (int i = 0; i <= K; ++i) {
    double s = 0.0;
    #pragma unroll
    for (int j = 0; j <= K; ++j) {
      int lo = i < j ? i : j, hi = i < j ? j : i;
      s += tri[lo * SP - lo * (lo + 1) / 2 + hi] * c0sel[j];
    }
    h[i] = s;
  }
  #pragma unroll
  for (int i = 0; i < K; ++i) cc[i] = h[i] - cc[i];
  cc[K] = h[K];
}

__global__ __launch_bounds__(256) void k_fused(const float* __restrict__ z,
                                               const float* __restrict__ D,
                                               const double* __restrict__ DtD,
                                               float* __restrict__ coefOut,
                                               int* __restrict__ idxWs,
                                               double* __restrict__ cWs,
                                               double* __restrict__ csumWs) {
  __shared__ float Dlds[8 * 512];    // 16 KB: one 8-row tile of D
  __shared__ float zbuf[64 * 8];     // 2 KB: [e][sig] for the block's 8 signals
  int tid = threadIdx.x;
  int lane = tid & 63;
  int wv = tid >> 6;                 // wave id 0..3 -> signals 2wv, 2wv+1
  int li = lane & 31;
  int g  = lane >> 5;                // scan group: signal 2wv+g
  int n = blockIdx.x * 8 + 2 * wv + g;
  // ---- stage z: zbuf[e*8+sig] = z[b, e, p0+sig] ----
  {
    int n0 = blockIdx.x * 8;
    int b = n0 >> 10, p0 = n0 & 1023;
    const float* zb = z + (size_t)b * 65536 + p0;
    #pragma unroll
    for (int k2 = 0; k2 < 2; ++k2) {
      int f = tid + 256 * k2;
      zbuf[f] = zb[(f >> 3) * 1024 + (f & 7)];
    }
  }
  // ---- corr phase: 8 tiles of 8 e-rows; lane owns atoms {4l..4l+3} U {256+4l..+3} ----
  double cA[8], cB[8];
  #pragma unroll
  for (int p = 0; p < 8; ++p) { cA[p] = 0.0; cB[p] = 0.0; }
  for (int t8 = 0; t8 < 8; ++t8) {
    __syncthreads();   // protect Dlds before overwrite (also covers zbuf on t8=0)
    {
      // global_load_lds width=16: dest = wave-uniform base + lane*16 (linear)
      #pragma unroll
      for (int i = 0; i < 4; ++i) {
        const float* gp = D + t8 * 4096 + i * 1024 + wv * 256 + lane * 4;
        float* lp = Dlds + i * 1024 + wv * 256;   // wave-uniform LDS base
        __builtin_amdgcn_global_load_lds(
            (const __attribute__((address_space(1))) void*)gp,
            (__attribute__((address_space(3))) void*)lp, 16, 0, 0);
      }
    }
    __syncthreads();   // barrier drains vmcnt -> tile visible
    #pragma unroll
    for (int e = 0; e < 8; ++e) {
      float2 zz = *(const float2*)(zbuf + (t8 * 8 + e) * 8 + 2 * wv);
      double zA = (double)zz.x, zB = (double)zz.y;
      const float* drow = Dlds + e * 512;
      float4 d0 = *(const float4*)(drow + lane * 4);         // atoms 4l..4l+3
      float4 d1 = *(const float4*)(drow + 256 + lane * 4);   // atoms 256+4l..+3
      double dv[8] = {(double)d0.x, (double)d0.y, (double)d0.z, (double)d0.w,
                      (double)d1.x, (double)d1.y, (double)d1.z, (double)d1.w};
      #pragma unroll
      for (int p = 0; p < 8; ++p) {
        cA[p] += zA * dv[p];
        cB[p] += zB * dv[p];
      }
    }
  }
  // ---- exchange corr layout -> scan layout (bit-identical values) ----
  // c0[4*j4+bit] = (g? cB:cA)[4*(j4>>1)+bit] held by lane 32*(j4&1)+li
  double c0[16];
  #pragma unroll
  for (int j4 = 0; j4 < 4; ++j4) {
    int src = ((j4 & 1) << 5) + li;
    #pragma unroll
    for (int bit = 0; bit < 4; ++bit) {
      double tA = __shfl(cA[((j4 >> 1) << 2) + bit], src, 64);
      double tB = __shfl(cB[((j4 >> 1) << 2) + bit], src, 64);
      c0[4 * j4 + bit] = g ? tB : tA;
    }
  }
  // ---- OMP iterations (scan layout unchanged) ----
  unsigned amask = 0;
  int idx[SP]; double cc[SP]; double tri[15]; double c0sel[SP];
  omp_iter<0>(DtD, c0, amask, idx, cc, tri, c0sel, li);
  omp_iter<1>(DtD, c0, amask, idx, cc, tri, c0sel, li);
  omp_iter<2>(DtD, c0, amask, idx, cc, tri, c0sel, li);
  omp_iter<3>(DtD, c0, amask, idx, cc, tri, c0sel, li);
  omp_iter<4>(DtD, c0, amask, idx, cc, tri, c0sel, li);
  if (li == 0) {
    double cs = 0.0;
    #pragma unroll
    for (int j = 0; j < SP; ++j) {
      double cj = cc[j];
      cj = fmin(fmax(cj, -10000000.0), 10000000.0);   // COEFF_CLAMP
      cs += fabs(cj);
      idxWs[n * SP + j] = idx[j];
      cWs[n * SP + j] = cj;
      coefOut[(size_t)idx[j] * NSIG + n] = (float)cj;
    }
    csumWs[n] = cs;
  }
}

// ---------------- kernel D: z_q + per-block rec-loss partials ----------------
__global__ __launch_bounds__(256) void k_zq(const float* __restrict__ z,
                                            const float* __restrict__ D,
                                            const int* __restrict__ idxWs,
                                            const double* __restrict__ cWs,
                                            float* __restrict__ zqOut,
                                            double* __restrict__ recWs) {
  int t = threadIdx.x;
  size_t flat = (size_t)blockIdx.x * 256 + t;   // indexes z / z_q directly
  int b = (int)(flat >> 16);
  int e = (int)((flat >> 10) & 63);
  int p = (int)(flat & 1023);
  int n = b * 1024 + p;
  double u = 0.0;
  #pragma unroll
  for (int j = 0; j < SP; ++j) {
    int a = idxWs[n * SP + j];
    u += (double)D[e * KD + a] * cWs[n * SP + j];
  }
  float zv = z[flat];
  double d = u - (double)zv;
  double dc = fmin(fmax(d, -1.0), 1.0);
  zqOut[flat] = (float)((double)zv + dc);
  __shared__ double red[256];
  red[t] = d * d;
  __syncthreads();
  #pragma unroll
  for (int s = 128; s >= 1; s >>= 1) {
    if (t < s) red[t] += red[t + s];
    __syncthreads();
  }
  if (t == 0) recWs[blockIdx.x] = red[0];
}

// ---------------- kernel E: deterministic final reduction -> loss ----------------
__global__ __launch_bounds__(256) void k_loss(const double* __restrict__ recWs,
                                              const double* __restrict__ csumWs,
                                              float* __restrict__ lossOut) {
  int t = threadIdx.x;
  double r = 0.0, c = 0.0;
  for (int i = t; i < 8192; i += 256) r += recWs[i];
  for (int i = t; i < NSIG; i += 256) c += csumWs[i];
  __shared__ double red[512];
  red[t] = r; red[256 + t] = c;
  __syncthreads();
  #pragma unroll
  for (int s = 128; s >= 1; s >>= 1) {
    if (t < s) { red[t] += red[t + s]; red[256 + t] += red[256 + t + s]; }
    __syncthreads();
  }
  if (t == 0) {
    double rec = red[0] / (double)(64.0 * 32768.0);
    double cm  = red[256] / (double)(512.0 * 32768.0);
    // loss = rec + 0.25*(1+5/10)*commit + 1e-3*coeff ; commit == rec numerically
    double loss = rec + 0.375 * rec + 0.001 * cm;
    lossOut[0] = (float)loss;
  }
}

extern "C" void kernel_launch(void* const* d_in, const int* in_sizes, int n_in,
                              void* d_out, int out_size, void* d_ws, size_t ws_size,
                              hipStream_t stream) {
  const float* z = (const float*)d_in[0];       // (32,64,32,32)
  const float* D = (const float*)d_in[1];       // (64,512)
  float* out = (float*)d_out;
  float* zqOut   = out;                         // 2097152
  float* lossOut = out + 2097152;               // 1
  float* coefOut = out + 2097153;               // 512*32768

  // workspace carve (all 8B-aligned offsets)
  char* w = (char*)d_ws;
  double* DtD    = (double*)w; w += (size_t)KD * KD * 8;        // 2 MB
  int*    idxWs  = (int*)w;    w += (size_t)NSIG * SP * 4;      // 640 KB
  double* cWs    = (double*)w; w += (size_t)NSIG * SP * 8;      // 1.25 MB
  double* csumWs = (double*)w; w += (size_t)NSIG * 8;           // 256 KB
  double* recWs  = (double*)w; w += (size_t)8192 * 8;           // 64 KB

  k_pre<<<3072, 256, 0, stream>>>(D, DtD, (float4*)coefOut);
  k_fused<<<NSIG / 8, 256, 0, stream>>>(z, D, DtD, coefOut, idxWs, cWs, csumWs);
  k_zq<<<8192, 256, 0, stream>>>(z, D, idxWs, cWs, zqOut, recWs);
  k_loss<<<1, 256, 0, stream>>>(recWs, csumWs, lossOut);
}